// Round 10
// baseline (238.351 us; speedup 1.0000x reference)
//
#include <hip/hip_runtime.h>
#include <stdint.h>

static constexpr int kNU = 100000;
static constexpr int kNI = 50000;
static constexpr int kE  = 500000;
static constexpr int kC  = 128;
static constexpr int kB  = 1024;
static constexpr int kNBK = 256;  // binning blocks per direction
static constexpr int kCap = 4096; // max edges per coarse bucket (mean 2560)

typedef __attribute__((ext_vector_type(8))) short bf16x8;
typedef __attribute__((ext_vector_type(4))) float f32x4;

__device__ __forceinline__ unsigned short f2bf(float f) {
  unsigned u = __float_as_uint(f);
  unsigned r = (u + 0x7fffu + ((u >> 16) & 1u)) >> 16;
  return (unsigned short)r;
}

// async global->LDS, 16B per lane; LDS dest is wave-uniform base + lane*16
__device__ __forceinline__ void gload_lds16(const unsigned short* g, unsigned short* l) {
  __builtin_amdgcn_global_load_lds(
      (const __attribute__((address_space(1))) unsigned int*)g,
      (__attribute__((address_space(3))) unsigned int*)l, 16, 0, 0);
}

// ===== dispatch 1: cvt (fp32->bf16 + 4 pad rows) ++ prep_w ++ needinit =====
// block-range fused: [0,CVT) cvt, [CVT,CVT+512) prep_w, rest needinit.
__global__ void setup_kernel(const float* __restrict__ xu, const float* __restrict__ xi,
                             unsigned short* __restrict__ fu0, unsigned short* __restrict__ fu1,
                             unsigned short* __restrict__ fi0, unsigned short* __restrict__ fi1,
                             const float* __restrict__ wrel, const float* __restrict__ wroot,
                             unsigned short* __restrict__ wcat,
                             unsigned* __restrict__ mark, int* __restrict__ rlist,
                             int* __restrict__ cnt, int cvtBlks) {
  int b = blockIdx.x;
  int tid = threadIdx.x;
  if (b < cvtBlks) {
    int i = b * 256 + tid;  // float4 index
    const int nu4 = kNU * kC / 4;
    const int ni4 = kNI * kC / 4;
    if (i < nu4) {
      float4 v = ((const float4*)xu)[i];
      ushort4 o; o.x = f2bf(v.x); o.y = f2bf(v.y); o.z = f2bf(v.z); o.w = f2bf(v.w);
      ((ushort4*)fu0)[i] = o;
    } else if (i < nu4 + ni4) {
      int j = i - nu4;
      float4 v = ((const float4*)xi)[j];
      ushort4 o; o.x = f2bf(v.x); o.y = f2bf(v.y); o.z = f2bf(v.z); o.w = f2bf(v.w);
      ((ushort4*)fi0)[j] = o;
    } else {
      int j = i - nu4 - ni4;  // 0..127: 4 pad rows x 32 ushort4 each
      if (j < 128) {
        int w = j >> 5;
        int o = j & 31;
        unsigned short* dst = (w == 0) ? fu0 + (size_t)kNU * kC
                            : (w == 1) ? fu1 + (size_t)kNU * kC
                            : (w == 2) ? fi0 + (size_t)kNI * kC
                                       : fi1 + (size_t)kNI * kC;
        ushort4 z; z.x = 0; z.y = 0; z.z = 0; z.w = 0;
        ((ushort4*)dst)[o] = z;
      }
    }
  } else if (b < cvtBlks + 512) {
    int id = (b - cvtBlks) * 256 + tid;  // 4*128*256 = 131072
    int m = id >> 15;
    int n = (id >> 8) & 127;
    int k = id & 255;
    float v = (k < 128) ? wrel[(m * 128 + k) * 128 + n] : wroot[(m * 128 + (k - 128)) * 128 + n];
    wcat[id] = f2bf(v);
  } else {
    int i = (b - cvtBlks - 512) * 256 + tid;
    if (i < (kNI + 31) / 32) mark[i] = 0;
    if (i < kNI + 128) rlist[i] = kNI;  // sentinel = fi pad row; masked at store
    if (i == 0) *cnt = 0;
  }
}

// ===== dispatch 2: binA (both dirs) ++ mark (items feeding users < kB) =====
__global__ void edge_kernel(const int* __restrict__ dst_i, const int* __restrict__ dst_u,
                            int* __restrict__ bh_i, int* __restrict__ bh_u,
                            const int* __restrict__ msrc, const int* __restrict__ mdst,
                            unsigned* __restrict__ mark) {
  __shared__ int h[256];
  int b = blockIdx.x;
  int tid = threadIdx.x;
  if (b < 2 * kNBK) {
    const int* dst;
    int shift;
    int* bh;
    int blk;
    if (b < kNBK) { dst = dst_i; shift = 8; bh = bh_i; blk = b; }
    else          { dst = dst_u; shift = 9; bh = bh_u; blk = b - kNBK; }
    h[tid] = 0;
    __syncthreads();
    int chunk = (kE + kNBK - 1) / kNBK;
    int beg = blk * chunk;
    int end = min(kE, beg + chunk);
    for (int i = beg + tid; i < end; i += 256) atomicAdd(&h[dst[i] >> shift], 1);
    __syncthreads();
    bh[blk * 256 + tid] = h[tid];
  } else {
    int i = (b - 2 * kNBK) * 256 + tid;
    if (i < kE && mdst[i] < kB) {
      int it = msrc[i];
      atomicOr(&mark[it >> 5], 1u << (it & 31));
    }
  }
}

// ===== dispatch 3: binB (2 blocks) ++ compact (needed-item list) =====
__global__ void scan_kernel(const int* __restrict__ bh_i, int* __restrict__ bo_i,
                            int* __restrict__ base_i, const int* __restrict__ bh_u,
                            int* __restrict__ bo_u, int* __restrict__ base_u,
                            const unsigned* __restrict__ mark, int* __restrict__ rlist,
                            int* __restrict__ cnt) {
  __shared__ int s[256];
  int b = blockIdx.x;
  int t = threadIdx.x;
  if (b < 2) {
    const int* bh;
    int* bo;
    int* base;
    if (b == 0) { bh = bh_i; bo = bo_i; base = base_i; }
    else        { bh = bh_u; bo = bo_u; base = base_u; }
    int run = 0;
    for (int bb = 0; bb < kNBK; ++bb) {
      int v = bh[bb * 256 + t];
      bo[bb * 256 + t] = run;
      run += v;
    }
    s[t] = run;
    __syncthreads();
    for (int m = 1; m < 256; m <<= 1) {
      int tv = 0;
      if (t >= m) tv = s[t - m];
      __syncthreads();
      s[t] += tv;
      __syncthreads();
    }
    base[t] = s[t] - run;
    if (t == 255) base[256] = s[255];
  } else {
    int i = (b - 2) * 256 + t;
    if (i < kNI && ((mark[i >> 5] >> (i & 31)) & 1u)) {
      int p = atomicAdd(cnt, 1);
      rlist[p] = i;  // unordered ok: rows independent
    }
  }
}

__global__ void binC_kernel(const int* __restrict__ src_i, const int* __restrict__ dst_i,
                            const int* __restrict__ bo_i, const int* __restrict__ base_i,
                            unsigned* __restrict__ packed_i, const int* __restrict__ src_u,
                            const int* __restrict__ dst_u, const int* __restrict__ bo_u,
                            const int* __restrict__ base_u, unsigned* __restrict__ packed_u) {
  __shared__ int cur[256];
  int b = blockIdx.x;
  const int *src, *dst, *bo, *base;
  unsigned* packed;
  int shift, blk;
  if (b < kNBK) { src = src_i; dst = dst_i; bo = bo_i; base = base_i; packed = packed_i; shift = 8; blk = b; }
  else          { src = src_u; dst = dst_u; bo = bo_u; base = base_u; packed = packed_u; shift = 9; blk = b - kNBK; }
  int tid = threadIdx.x;
  cur[tid] = base[tid] + bo[blk * 256 + tid];
  __syncthreads();
  int chunk = (kE + kNBK - 1) / kNBK;
  int beg = blk * chunk;
  int end = min(kE, beg + chunk);
  int mask = (1 << shift) - 1;
  for (int i = beg + tid; i < end; i += 256) {
    int d = dst[i];
    int p = atomicAdd(&cur[d >> shift], 1);
    packed[p] = (unsigned)src[i] | ((unsigned)(d & mask) << 17);
  }
}

__launch_bounds__(256)
__global__ void binD_kernel(const unsigned* __restrict__ packed_i, const int* __restrict__ base_i,
                            int* __restrict__ col_i, int* __restrict__ rowptr_i,
                            const unsigned* __restrict__ packed_u, const int* __restrict__ base_u,
                            int* __restrict__ col_u, int* __restrict__ rowptr_u) {
  __shared__ unsigned ent[kCap];
  __shared__ int srt[kCap];
  __shared__ int hist[512];
  __shared__ int cur[512];
  int b = blockIdx.x;
  const unsigned* packed;
  const int* base;
  int* col;
  int* rowptr;
  int bsize, Nd, bb;
  if (b < 196) { packed = packed_i; base = base_i; col = col_i; rowptr = rowptr_i; bsize = 256; Nd = kNI; bb = b; }
  else         { packed = packed_u; base = base_u; col = col_u; rowptr = rowptr_u; bsize = 512; Nd = kNU; bb = b - 196; }
  int tid = threadIdx.x;
  int seg_beg = base[bb], seg_end = base[bb + 1];
  int cnt = seg_end - seg_beg;
  if (cnt > kCap) cnt = kCap;
  hist[tid] = 0;
  hist[tid + 256] = 0;
  __syncthreads();
  for (int i = tid; i < cnt; i += 256) {
    unsigned e = packed[seg_beg + i];
    ent[i] = e;
    atomicAdd(&hist[e >> 17], 1);
  }
  __syncthreads();
  for (int d = 1; d < 512; d <<= 1) {
    int idx = (tid + 1) * 2 * d - 1;
    if (idx < 512) hist[idx] += hist[idx - d];
    __syncthreads();
  }
  if (tid == 0) hist[511] = 0;
  __syncthreads();
  for (int d = 256; d >= 1; d >>= 1) {
    int idx = (tid + 1) * 2 * d - 1;
    if (idx < 512) {
      int tmp = hist[idx - d];
      hist[idx - d] = hist[idx];
      hist[idx] += tmp;
    }
    __syncthreads();
  }
  for (int j = tid; j < bsize; j += 256) {
    int n = bb * bsize + j;
    if (n < Nd) rowptr[n] = seg_beg + hist[j];
  }
  if (bb == 195 && tid == 0) rowptr[Nd] = seg_end;
  cur[tid] = hist[tid];
  cur[tid + 256] = hist[tid + 256];
  __syncthreads();
  for (int i = tid; i < cnt; i += 256) {
    unsigned e = ent[i];
    int p = atomicAdd(&cur[e >> 17], 1);
    srt[p] = (int)(e & 0x1FFFFu);
  }
  __syncthreads();
  for (int i = tid; i < cnt; i += 256) col[seg_beg + i] = srt[i];
}

// ===== fused pull+gemm(+head) v12: per block (256 thr / 4 waves / 128 slots):
// phase G gathers neighbor features (pull4 body: quarter-wave/row, 8-deep, zero-pad
// clamp) -> bf16 -> Ws (XOR-swizzled); A-frags read back; Ws reused for K-split W
// staging (gemm10/11 path); LN epilogue; optional fused head (in-register dot with
// lin_w from the bf16-rounded outputs, 16-lane shuffle reduce). Item side runs in
// SLOT space via rlist/cnt (sentinel kNI = zero pad row, masked at store).
__launch_bounds__(256, 4)
__global__ void fused12_kernel(int nbi, int do_head,
                               const int* __restrict__ rlist, const int* __restrict__ pcnt,
                               const int* __restrict__ rp_i, const int* __restrict__ col_i,
                               const unsigned short* __restrict__ gs_i, const unsigned short* __restrict__ ft_i,
                               const unsigned short* __restrict__ wc_i, const float* __restrict__ bs_i,
                               const float* __restrict__ gm_i, const float* __restrict__ bt_i,
                               unsigned short* __restrict__ out_i,
                               const int* __restrict__ rp_u, const int* __restrict__ col_u,
                               const unsigned short* __restrict__ gs_u, const unsigned short* __restrict__ ft_u,
                               const unsigned short* __restrict__ wc_u, const float* __restrict__ bs_u,
                               const float* __restrict__ gm_u, const float* __restrict__ bt_u,
                               unsigned short* __restrict__ out_u,
                               const float* __restrict__ lw, const float* __restrict__ lb,
                               float* __restrict__ dout) {
  __shared__ __attribute__((aligned(16))) unsigned short Ws[128 * 128];  // 32 KB: A-tile, then W
  int b = blockIdx.x;
  bool ind = (b < nbi);
  const int *rowptr, *col;
  const unsigned short *gsrc, *feat, *wcat;
  const float *bias, *gamma, *beta;
  unsigned short* out;
  int N, row0, NZ;
  if (ind) {
    rowptr = rp_i; col = col_i; gsrc = gs_i; feat = ft_i; wcat = wc_i;
    bias = bs_i; gamma = gm_i; beta = bt_i; out = out_i;
    N = kNI; row0 = b * 128; NZ = kNU;
  } else {
    rowptr = rp_u; col = col_u; gsrc = gs_u; feat = ft_u; wcat = wc_u;
    bias = bs_u; gamma = gm_u; beta = bt_u; out = out_u;
    N = kNU; row0 = (b - nbi) * 128; NZ = kNI;
  }
  int cnt = ind ? *pcnt : N;
  if (row0 >= cnt) return;  // block-uniform, before any barrier
  int tid = threadIdx.x;
  int lane = tid & 63;
  int wv = tid >> 6;  // 0..3
  int q = lane >> 4;
  int c0 = lane & 15;

  // ---- phase G: gather this block's 128 slots into Ws (swizzled bf16) ----
  {
    int choff = c0 * 8;  // lane covers channels c0*8 .. +8
    for (int rr = 0; rr < 8; ++rr) {
      int rloc = wv * 32 + rr * 4 + q;
      int slot = row0 + rloc;
      bool valid = slot < cnt;
      int beg = 0, end = 0;
      if (valid) {
        int r = ind ? rlist[slot] : slot;
        beg = rowptr[r];
        end = rowptr[r + 1];
      }
      float acc[8];
#pragma unroll
      for (int cch = 0; cch < 8; ++cch) acc[cch] = 0.f;
      int idx[8];
#pragma unroll
      for (int i = 0; i < 8; ++i) idx[i] = (beg + i < end) ? col[beg + i] : NZ;
      for (int j = beg; j < end; j += 8) {
        int nxt[8];
#pragma unroll
        for (int i = 0; i < 8; ++i) {
          int jj = j + 8 + i;
          nxt[i] = (jj < end) ? col[jj] : NZ;
        }
        uint4 g0 = *(const uint4*)(gsrc + (size_t)idx[0] * kC + choff);
        uint4 g1 = *(const uint4*)(gsrc + (size_t)idx[1] * kC + choff);
        uint4 g2 = *(const uint4*)(gsrc + (size_t)idx[2] * kC + choff);
        uint4 g3 = *(const uint4*)(gsrc + (size_t)idx[3] * kC + choff);
        uint4 g4 = *(const uint4*)(gsrc + (size_t)idx[4] * kC + choff);
        uint4 g5 = *(const uint4*)(gsrc + (size_t)idx[5] * kC + choff);
        uint4 g6 = *(const uint4*)(gsrc + (size_t)idx[6] * kC + choff);
        uint4 g7 = *(const uint4*)(gsrc + (size_t)idx[7] * kC + choff);
#define ACC8(g)                                          \
        acc[0] += __uint_as_float((g).x << 16);          \
        acc[1] += __uint_as_float((g).x & 0xffff0000u);  \
        acc[2] += __uint_as_float((g).y << 16);          \
        acc[3] += __uint_as_float((g).y & 0xffff0000u);  \
        acc[4] += __uint_as_float((g).z << 16);          \
        acc[5] += __uint_as_float((g).z & 0xffff0000u);  \
        acc[6] += __uint_as_float((g).w << 16);          \
        acc[7] += __uint_as_float((g).w & 0xffff0000u);
        ACC8(g0)
        ACC8(g1)
        ACC8(g2)
        ACC8(g3)
        ACC8(g4)
        ACC8(g5)
        ACC8(g6)
        ACC8(g7)
#undef ACC8
#pragma unroll
        for (int i = 0; i < 8; ++i) idx[i] = nxt[i];
      }
      uint4 o;
      o.x = (unsigned)f2bf(acc[0]) | ((unsigned)f2bf(acc[1]) << 16);
      o.y = (unsigned)f2bf(acc[2]) | ((unsigned)f2bf(acc[3]) << 16);
      o.z = (unsigned)f2bf(acc[4]) | ((unsigned)f2bf(acc[5]) << 16);
      o.w = (unsigned)f2bf(acc[6]) | ((unsigned)f2bf(acc[7]) << 16);
      *(uint4*)&Ws[rloc * 128 + ((c0 ^ (rloc & 7)) * 8)] = o;
    }
  }
  __syncthreads();

  // ---- A-frags (gathered agg) from LDS, swizzled read ----
  int rsw = c0 & 7;
  bf16x8 aA[4], aB[4];
#pragma unroll
  for (int ks = 0; ks < 4; ++ks) {
    int chp = ((ks * 4 + q) ^ rsw) * 8;
    aA[ks] = *(const bf16x8*)&Ws[(wv * 32 + c0) * 128 + chp];
    aB[ks] = *(const bf16x8*)&Ws[(wv * 32 + 16 + c0) * 128 + chp];
  }
  __syncthreads();  // all waves done reading gathered A-tile

  // ---- stage 0: w_rel half (k<128) into Ws (overwrite) ----
  {
    int p0 = lane & 15;
    int rsub = lane >> 4;
#pragma unroll
    for (int o8 = 0; o8 < 8; ++o8) {
      int n = wv * 32 + o8 * 4 + rsub;
      int j = p0 ^ (n & 7);
      gload_lds16(wcat + n * 256 + j * 8, &Ws[(wv * 32 + o8 * 4) * 128]);
    }
  }
  int rs = row0 + wv * 32;
  int slotA = rs + c0;
  int slotB = rs + 16 + c0;
  int rowAf = ind ? ((slotA < cnt) ? rlist[slotA] : kNI) : slotA;  // root-feat rows
  int rowBf = ind ? ((slotB < cnt) ? rlist[slotB] : kNI) : slotB;
  size_t baseAf = (size_t)rowAf * kC;
  size_t baseBf = (size_t)rowBf * kC;
  f32x4 accA[8], accB[8];
#pragma unroll
  for (int nt = 0; nt < 8; ++nt) {
    accA[nt] = (f32x4){0.f, 0.f, 0.f, 0.f};
    accB[nt] = (f32x4){0.f, 0.f, 0.f, 0.f};
  }
  asm volatile("s_waitcnt vmcnt(0)" ::: "memory");
  __syncthreads();

  // ---- half 0: B = w_rel, A = gathered agg; prefetch root-feat frags ----
#pragma unroll
  for (int ks = 0; ks < 4; ++ks) {
    int chp = ((ks * 4 + q) ^ rsw) * 8;
#pragma unroll
    for (int nt = 0; nt < 8; ++nt) {
      bf16x8 bfr = *(const bf16x8*)&Ws[(nt * 16 + c0) * 128 + chp];
      accA[nt] = __builtin_amdgcn_mfma_f32_16x16x32_bf16(aA[ks], bfr, accA[nt], 0, 0, 0);
      accB[nt] = __builtin_amdgcn_mfma_f32_16x16x32_bf16(aB[ks], bfr, accB[nt], 0, 0, 0);
    }
    aA[ks] = *(const bf16x8*)(feat + baseAf + ks * 32 + q * 8);
    aB[ks] = *(const bf16x8*)(feat + baseBf + ks * 32 + q * 8);
  }

  __syncthreads();  // all waves done reading Ws (half 0)
  // ---- stage 1: w_root half (k>=128) ----
  {
    int p0 = lane & 15;
    int rsub = lane >> 4;
#pragma unroll
    for (int o8 = 0; o8 < 8; ++o8) {
      int n = wv * 32 + o8 * 4 + rsub;
      int j = p0 ^ (n & 7);
      gload_lds16(wcat + n * 256 + 128 + j * 8, &Ws[(wv * 32 + o8 * 4) * 128]);
    }
  }
  asm volatile("s_waitcnt vmcnt(0)" ::: "memory");
  __syncthreads();

  // ---- half 1: B = w_root, A = root feats ----
#pragma unroll
  for (int ks = 0; ks < 4; ++ks) {
    int chp = ((ks * 4 + q) ^ rsw) * 8;
#pragma unroll
    for (int nt = 0; nt < 8; ++nt) {
      bf16x8 bfr = *(const bf16x8*)&Ws[(nt * 16 + c0) * 128 + chp];
      accA[nt] = __builtin_amdgcn_mfma_f32_16x16x32_bf16(aA[ks], bfr, accA[nt], 0, 0, 0);
      accB[nt] = __builtin_amdgcn_mfma_f32_16x16x32_bf16(aB[ks], bfr, accB[nt], 0, 0, 0);
    }
  }

  // LN/head constants after main loop
  float bcol[8], gcol[8], ecol[8], lwc[8];
#pragma unroll
  for (int nt = 0; nt < 8; ++nt) {
    bcol[nt] = bias[nt * 16 + c0];
    gcol[nt] = gamma[nt * 16 + c0];
    ecol[nt] = beta[nt * 16 + c0];
    lwc[nt] = lw[nt * 16 + c0];
  }

  // intra-wave LN epilogue + optional fused head
#pragma unroll
  for (int half = 0; half < 2; ++half) {
    int sbh = rs + half * 16;
#pragma unroll
    for (int reg = 0; reg < 4; ++reg) {
      int slot_r = sbh + q * 4 + reg;
      float v[8];
      float s1 = 0.f, s2 = 0.f;
#pragma unroll
      for (int nt = 0; nt < 8; ++nt) {
        float t = (half ? accB[nt][reg] : accA[nt][reg]) + bcol[nt];
        v[nt] = t;
        s1 += t;
        s2 += t * t;
      }
#pragma unroll
      for (int m = 1; m < 16; m <<= 1) {
        s1 += __shfl_xor(s1, m, 64);
        s2 += __shfl_xor(s2, m, 64);
      }
      float mu = s1 * (1.f / 128.f);
      float var = s2 * (1.f / 128.f) - mu * mu;
      float rsq = rsqrtf(var + 1e-5f);
      int row = ind ? ((slot_r < cnt) ? rlist[slot_r] : N) : slot_r;
      if (row < N) {
        float hs = 0.f;
#pragma unroll
        for (int nt = 0; nt < 8; ++nt) {
          float o = fmaxf((v[nt] - mu) * rsq * gcol[nt] + ecol[nt], 0.f);
          unsigned short h = f2bf(o);
          if (do_head) hs += __uint_as_float((unsigned)h << 16) * lwc[nt];
          unsigned up = __shfl_xor((unsigned)h, 1, 64);
          if ((lane & 1) == 0) {
            *(unsigned*)(out + (size_t)row * kC + nt * 16 + c0) = (unsigned)h | (up << 16);
          }
        }
        if (do_head) {
#pragma unroll
          for (int m = 1; m < 16; m <<= 1) hs += __shfl_xor(hs, m, 64);
          if (c0 == 0) dout[row] = hs + lb[0];
        }
      }
    }
  }
}

extern "C" void kernel_launch(void* const* d_in, const int* in_sizes, int n_in,
                              void* d_out, int out_size, void* d_ws, size_t ws_size,
                              hipStream_t stream) {
  const float* x_user = (const float*)d_in[0];
  const float* x_item = (const float*)d_in[1];
  const int* e_ui_src = (const int*)d_in[2];
  const int* e_ui_dst = (const int*)d_in[3];
  const int* e_iu_src = (const int*)d_in[4];
  const int* e_iu_dst = (const int*)d_in[5];
  const float* w_rel  = (const float*)d_in[6];
  const float* w_root = (const float*)d_in[7];
  const float* bvec   = (const float*)d_in[8];
  const float* ln_g   = (const float*)d_in[9];
  const float* ln_b   = (const float*)d_in[10];
  const float* lin_w  = (const float*)d_in[11];
  const float* lin_b  = (const float*)d_in[12];

  char* p = (char*)d_ws;
  auto carve = [&](size_t bytes) -> char* {
    char* r = p;
    p += (bytes + 255) & ~size_t(255);
    return r;
  };
  // +1 pad row (zeros, written by setup) on each feature table
  unsigned short* fu[2] = {(unsigned short*)carve((size_t)(kNU + 1) * kC * 2),
                           (unsigned short*)carve((size_t)(kNU + 1) * kC * 2)};
  unsigned short* fi[2] = {(unsigned short*)carve((size_t)(kNI + 1) * kC * 2),
                           (unsigned short*)carve((size_t)(kNI + 1) * kC * 2)};
  unsigned short* wcat  = (unsigned short*)carve((size_t)4 * 128 * 256 * 2);
  int* bh_i   = (int*)carve((size_t)kNBK * 256 * 4);
  int* bo_i   = (int*)carve((size_t)kNBK * 256 * 4);
  int* bh_u   = (int*)carve((size_t)kNBK * 256 * 4);
  int* bo_u   = (int*)carve((size_t)kNBK * 256 * 4);
  int* base_i = (int*)carve(257 * 4);
  int* base_u = (int*)carve(257 * 4);
  unsigned* packed_i = (unsigned*)carve((size_t)kE * 4);
  unsigned* packed_u = (unsigned*)carve((size_t)kE * 4);
  int* col_i    = (int*)carve((size_t)(kE + 4) * 4);
  int* col_u    = (int*)carve((size_t)(kE + 4) * 4);
  int* rowptr_i = (int*)carve((size_t)(kNI + 1) * 4);
  int* rowptr_u = (int*)carve((size_t)(kNU + 1) * 4);
  unsigned* mark = (unsigned*)carve(((kNI + 31) / 32) * 4);
  int* rlist = (int*)carve((size_t)(kNI + 128) * 4);
  int* cntp  = (int*)carve(4);

  // dispatch 1: cvt + prep_w + needinit
  int cvt4 = (kNU * kC + kNI * kC) / 4 + 128;
  int cvtBlks = (cvt4 + 255) / 256;                       // 18751
  int needBlks = (kNI + 128 + 255) / 256;                 // 197
  setup_kernel<<<cvtBlks + 512 + needBlks, 256, 0, stream>>>(
      x_user, x_item, fu[0], fu[1], fi[0], fi[1], w_rel, w_root, wcat,
      mark, rlist, cntp, cvtBlks);

  // dispatch 2: binA + mark
  int markBlks = (kE + 255) / 256;                        // 1954
  edge_kernel<<<2 * kNBK + markBlks, 256, 0, stream>>>(e_ui_dst, e_iu_dst, bh_i, bh_u,
                                                       e_iu_src, e_iu_dst, mark);
  // dispatch 3: binB + compact
  scan_kernel<<<2 + (kNI + 255) / 256, 256, 0, stream>>>(bh_i, bo_i, base_i,
                                                         bh_u, bo_u, base_u,
                                                         mark, rlist, cntp);
  // dispatch 4-5: CSR scatter + per-bucket sort
  binC_kernel<<<2 * kNBK, 256, 0, stream>>>(e_ui_src, e_ui_dst, bo_i, base_i, packed_i,
                                            e_iu_src, e_iu_dst, bo_u, base_u, packed_u);
  binD_kernel<<<392, 256, 0, stream>>>(packed_i, base_i, col_i, rowptr_i,
                                       packed_u, base_u, col_u, rowptr_u);

  int nbi_g = (kNI + 127) / 128; // 391 item blocks (most exit early past *cnt)
  int nbu_gB = kB / 128;         // 8 user blocks (rows < 1024)

  // dispatch 6: layer 0 fused gather+gemm (item needed-set in slot space + user<kB)
  fused12_kernel<<<nbi_g + nbu_gB, 256, 0, stream>>>(
      nbi_g, 0, rlist, cntp,
      rowptr_i, col_i, fu[0], fi[0], wcat + (size_t)0 * 128 * 256,
      bvec + (size_t)0 * kC, ln_g + (size_t)1 * kC, ln_b + (size_t)1 * kC, fi[1],
      rowptr_u, col_u, fi[0], fu[0], wcat + (size_t)1 * 128 * 256,
      bvec + (size_t)1 * kC, ln_g + (size_t)0 * kC, ln_b + (size_t)0 * kC, fu[1],
      lin_w, lin_b, (float*)d_out);

  // dispatch 7: layer 1 fused gather+gemm+head (user<kB only)
  fused12_kernel<<<nbu_gB, 256, 0, stream>>>(
      0, 1, rlist, cntp,
      rowptr_i, col_i, fu[1], fi[1], wcat + (size_t)2 * 128 * 256,
      bvec + (size_t)2 * kC, ln_g + (size_t)3 * kC, ln_b + (size_t)3 * kC, fi[0],
      rowptr_u, col_u, fi[1], fu[1], wcat + (size_t)3 * 128 * 256,
      bvec + (size_t)3 * kC, ln_g + (size_t)2 * kC, ln_b + (size_t)2 * kC, fu[0],
      lin_w, lin_b, (float*)d_out);
}

// Round 11
// 215.226 us; speedup vs baseline: 1.1074x; 1.1074x over previous
//
#include <hip/hip_runtime.h>
#include <stdint.h>

static constexpr int kNU = 100000;
static constexpr int kNI = 50000;
static constexpr int kE  = 500000;
static constexpr int kC  = 128;
static constexpr int kB  = 1024;
static constexpr int kNBK = 256;  // binning blocks per direction
static constexpr int kCap = 4096; // max edges per coarse bucket (mean 2560)
static constexpr int kMaxNeed = 5120;  // <=5120 edges reach users<kB -> <=5120 needed items

typedef __attribute__((ext_vector_type(8))) short bf16x8;
typedef __attribute__((ext_vector_type(4))) float f32x4;

__device__ __forceinline__ unsigned short f2bf(float f) {
  unsigned u = __float_as_uint(f);
  unsigned r = (u + 0x7fffu + ((u >> 16) & 1u)) >> 16;
  return (unsigned short)r;
}

// async global->LDS, 16B per lane; LDS dest is wave-uniform base + lane*16
__device__ __forceinline__ void gload_lds16(const unsigned short* g, unsigned short* l) {
  __builtin_amdgcn_global_load_lds(
      (const __attribute__((address_space(1))) unsigned int*)g,
      (__attribute__((address_space(3))) unsigned int*)l, 16, 0, 0);
}

// ===== dispatch 1: cvt (fp32->bf16 + 4 pad rows) ++ prep_w ++ needinit =====
__global__ void setup_kernel(const float* __restrict__ xu, const float* __restrict__ xi,
                             unsigned short* __restrict__ fu0, unsigned short* __restrict__ fu1,
                             unsigned short* __restrict__ fi0, unsigned short* __restrict__ fi1,
                             const float* __restrict__ wrel, const float* __restrict__ wroot,
                             unsigned short* __restrict__ wcat,
                             unsigned* __restrict__ mark, int* __restrict__ rlist,
                             int* __restrict__ cnt, int cvtBlks) {
  int b = blockIdx.x;
  int tid = threadIdx.x;
  if (b < cvtBlks) {
    int i = b * 256 + tid;  // float4 index
    const int nu4 = kNU * kC / 4;
    const int ni4 = kNI * kC / 4;
    if (i < nu4) {
      float4 v = ((const float4*)xu)[i];
      ushort4 o; o.x = f2bf(v.x); o.y = f2bf(v.y); o.z = f2bf(v.z); o.w = f2bf(v.w);
      ((ushort4*)fu0)[i] = o;
    } else if (i < nu4 + ni4) {
      int j = i - nu4;
      float4 v = ((const float4*)xi)[j];
      ushort4 o; o.x = f2bf(v.x); o.y = f2bf(v.y); o.z = f2bf(v.z); o.w = f2bf(v.w);
      ((ushort4*)fi0)[j] = o;
    } else {
      int j = i - nu4 - ni4;  // 0..127: 4 pad rows x 32 ushort4 each
      if (j < 128) {
        int w = j >> 5;
        int o = j & 31;
        unsigned short* dst = (w == 0) ? fu0 + (size_t)kNU * kC
                            : (w == 1) ? fu1 + (size_t)kNU * kC
                            : (w == 2) ? fi0 + (size_t)kNI * kC
                                       : fi1 + (size_t)kNI * kC;
        ushort4 z; z.x = 0; z.y = 0; z.z = 0; z.w = 0;
        ((ushort4*)dst)[o] = z;
      }
    }
  } else if (b < cvtBlks + 512) {
    int id = (b - cvtBlks) * 256 + tid;  // 4*128*256 = 131072
    int m = id >> 15;
    int n = (id >> 8) & 127;
    int k = id & 255;
    float v = (k < 128) ? wrel[(m * 128 + k) * 128 + n] : wroot[(m * 128 + (k - 128)) * 128 + n];
    wcat[id] = f2bf(v);
  } else {
    int i = (b - cvtBlks - 512) * 256 + tid;
    if (i < (kNI + 31) / 32) mark[i] = 0;
    if (i < kMaxNeed + 128) rlist[i] = kNI;  // sentinel = fi pad row; masked at store
    if (i == 0) *cnt = 0;
  }
}

// ===== dispatch 2: binA (both dirs) ++ mark (items feeding users < kB) =====
__global__ void edge_kernel(const int* __restrict__ dst_i, const int* __restrict__ dst_u,
                            int* __restrict__ bh_i, int* __restrict__ bh_u,
                            const int* __restrict__ msrc, const int* __restrict__ mdst,
                            unsigned* __restrict__ mark) {
  __shared__ int h[256];
  int b = blockIdx.x;
  int tid = threadIdx.x;
  if (b < 2 * kNBK) {
    const int* dst;
    int shift;
    int* bh;
    int blk;
    if (b < kNBK) { dst = dst_i; shift = 8; bh = bh_i; blk = b; }
    else          { dst = dst_u; shift = 9; bh = bh_u; blk = b - kNBK; }
    h[tid] = 0;
    __syncthreads();
    int chunk = (kE + kNBK - 1) / kNBK;
    int beg = blk * chunk;
    int end = min(kE, beg + chunk);
    for (int i = beg + tid; i < end; i += 256) atomicAdd(&h[dst[i] >> shift], 1);
    __syncthreads();
    bh[blk * 256 + tid] = h[tid];
  } else {
    int i = (b - 2 * kNBK) * 256 + tid;
    if (i < kE && mdst[i] < kB) {
      int it = msrc[i];
      atomicOr(&mark[it >> 5], 1u << (it & 31));
    }
  }
}

// ===== dispatch 3: binB (2 blocks) ++ compact (needed-item list) =====
__global__ void scan_kernel(const int* __restrict__ bh_i, int* __restrict__ bo_i,
                            int* __restrict__ base_i, const int* __restrict__ bh_u,
                            int* __restrict__ bo_u, int* __restrict__ base_u,
                            const unsigned* __restrict__ mark, int* __restrict__ rlist,
                            int* __restrict__ cnt) {
  __shared__ int s[256];
  int b = blockIdx.x;
  int t = threadIdx.x;
  if (b < 2) {
    const int* bh;
    int* bo;
    int* base;
    if (b == 0) { bh = bh_i; bo = bo_i; base = base_i; }
    else        { bh = bh_u; bo = bo_u; base = base_u; }
    int run = 0;
    for (int bb = 0; bb < kNBK; ++bb) {
      int v = bh[bb * 256 + t];
      bo[bb * 256 + t] = run;
      run += v;
    }
    s[t] = run;
    __syncthreads();
    for (int m = 1; m < 256; m <<= 1) {
      int tv = 0;
      if (t >= m) tv = s[t - m];
      __syncthreads();
      s[t] += tv;
      __syncthreads();
    }
    base[t] = s[t] - run;
    if (t == 255) base[256] = s[255];
  } else {
    int i = (b - 2) * 256 + t;
    if (i < kNI && ((mark[i >> 5] >> (i & 31)) & 1u)) {
      int p = atomicAdd(cnt, 1);
      rlist[p] = i;  // unordered ok: rows independent
    }
  }
}

__global__ void binC_kernel(const int* __restrict__ src_i, const int* __restrict__ dst_i,
                            const int* __restrict__ bo_i, const int* __restrict__ base_i,
                            unsigned* __restrict__ packed_i, const int* __restrict__ src_u,
                            const int* __restrict__ dst_u, const int* __restrict__ bo_u,
                            const int* __restrict__ base_u, unsigned* __restrict__ packed_u) {
  __shared__ int cur[256];
  int b = blockIdx.x;
  const int *src, *dst, *bo, *base;
  unsigned* packed;
  int shift, blk;
  if (b < kNBK) { src = src_i; dst = dst_i; bo = bo_i; base = base_i; packed = packed_i; shift = 8; blk = b; }
  else          { src = src_u; dst = dst_u; bo = bo_u; base = base_u; packed = packed_u; shift = 9; blk = b - kNBK; }
  int tid = threadIdx.x;
  cur[tid] = base[tid] + bo[blk * 256 + tid];
  __syncthreads();
  int chunk = (kE + kNBK - 1) / kNBK;
  int beg = blk * chunk;
  int end = min(kE, beg + chunk);
  int mask = (1 << shift) - 1;
  for (int i = beg + tid; i < end; i += 256) {
    int d = dst[i];
    int p = atomicAdd(&cur[d >> shift], 1);
    packed[p] = (unsigned)src[i] | ((unsigned)(d & mask) << 17);
  }
}

__launch_bounds__(256)
__global__ void binD_kernel(const unsigned* __restrict__ packed_i, const int* __restrict__ base_i,
                            int* __restrict__ col_i, int* __restrict__ rowptr_i,
                            const unsigned* __restrict__ packed_u, const int* __restrict__ base_u,
                            int* __restrict__ col_u, int* __restrict__ rowptr_u) {
  __shared__ unsigned ent[kCap];
  __shared__ int srt[kCap];
  __shared__ int hist[512];
  __shared__ int cur[512];
  int b = blockIdx.x;
  const unsigned* packed;
  const int* base;
  int* col;
  int* rowptr;
  int bsize, Nd, bb;
  if (b < 196) { packed = packed_i; base = base_i; col = col_i; rowptr = rowptr_i; bsize = 256; Nd = kNI; bb = b; }
  else         { packed = packed_u; base = base_u; col = col_u; rowptr = rowptr_u; bsize = 512; Nd = kNU; bb = b - 196; }
  int tid = threadIdx.x;
  int seg_beg = base[bb], seg_end = base[bb + 1];
  int cnt = seg_end - seg_beg;
  if (cnt > kCap) cnt = kCap;
  hist[tid] = 0;
  hist[tid + 256] = 0;
  __syncthreads();
  for (int i = tid; i < cnt; i += 256) {
    unsigned e = packed[seg_beg + i];
    ent[i] = e;
    atomicAdd(&hist[e >> 17], 1);
  }
  __syncthreads();
  for (int d = 1; d < 512; d <<= 1) {
    int idx = (tid + 1) * 2 * d - 1;
    if (idx < 512) hist[idx] += hist[idx - d];
    __syncthreads();
  }
  if (tid == 0) hist[511] = 0;
  __syncthreads();
  for (int d = 256; d >= 1; d >>= 1) {
    int idx = (tid + 1) * 2 * d - 1;
    if (idx < 512) {
      int tmp = hist[idx - d];
      hist[idx - d] = hist[idx];
      hist[idx] += tmp;
    }
    __syncthreads();
  }
  for (int j = tid; j < bsize; j += 256) {
    int n = bb * bsize + j;
    if (n < Nd) rowptr[n] = seg_beg + hist[j];
  }
  if (bb == 195 && tid == 0) rowptr[Nd] = seg_end;
  cur[tid] = hist[tid];
  cur[tid + 256] = hist[tid + 256];
  __syncthreads();
  for (int i = tid; i < cnt; i += 256) {
    unsigned e = ent[i];
    int p = atomicAdd(&cur[e >> 17], 1);
    srt[p] = (int)(e & 0x1FFFFu);
  }
  __syncthreads();
  for (int i = tid; i < cnt; i += 256) col[seg_beg + i] = srt[i];
}

// ---- pull aggregation v5: quarter-wave per row, 8-deep, zero-pad-row clamp.
// Item side in SLOT space via rlist/pcnt; user side direct. Short per-block
// critical path (1 row per quarter-wave) keeps the latency-bound tail cheap.
__global__ void pull5_kernel(const int* __restrict__ rp_i, const int* __restrict__ col_i,
                             const unsigned short* __restrict__ ft_i, unsigned short* __restrict__ ag_i,
                             const int* __restrict__ rp_u, const int* __restrict__ col_u,
                             const unsigned short* __restrict__ ft_u, unsigned short* __restrict__ ag_u,
                             const int* __restrict__ rlist, const int* __restrict__ pcnt,
                             int nbi) {
  int b = blockIdx.x;
  bool ind = (b < nbi);
  const int *rowptr, *col;
  const unsigned short* feat;
  unsigned short* agg;
  int Nd, rbase, NZ;
  if (ind) { rowptr = rp_i; col = col_i; feat = ft_i; agg = ag_i; Nd = kNI; rbase = b * 16; NZ = kNU; }
  else     { rowptr = rp_u; col = col_u; feat = ft_u; agg = ag_u; Nd = kNU; rbase = (b - nbi) * 16; NZ = kNI; }
  int cnt = ind ? *pcnt : Nd;
  if (rbase >= cnt) return;
  int tid = threadIdx.x;
  int wv = tid >> 6;
  int lane = tid & 63;
  int qrow = lane >> 4;
  int qoff = lane & 15;
  int slot = rbase + wv * 4 + qrow;
  bool valid = slot < cnt;
  int beg = 0, end = 0;
  if (valid) {
    int r = ind ? rlist[slot] : slot;
    beg = rowptr[r];
    end = rowptr[r + 1];
  }
  float acc[8];
#pragma unroll
  for (int c = 0; c < 8; ++c) acc[c] = 0.f;

  int idx[8];
#pragma unroll
  for (int i = 0; i < 8; ++i) idx[i] = (beg + i < end) ? col[beg + i] : NZ;

  int choff = qoff * 8;
  for (int j = beg; j < end; j += 8) {
    int nxt[8];
#pragma unroll
    for (int i = 0; i < 8; ++i) {
      int jj = j + 8 + i;
      nxt[i] = (jj < end) ? col[jj] : NZ;
    }
    uint4 g0 = *(const uint4*)(feat + (size_t)idx[0] * kC + choff);
    uint4 g1 = *(const uint4*)(feat + (size_t)idx[1] * kC + choff);
    uint4 g2 = *(const uint4*)(feat + (size_t)idx[2] * kC + choff);
    uint4 g3 = *(const uint4*)(feat + (size_t)idx[3] * kC + choff);
    uint4 g4 = *(const uint4*)(feat + (size_t)idx[4] * kC + choff);
    uint4 g5 = *(const uint4*)(feat + (size_t)idx[5] * kC + choff);
    uint4 g6 = *(const uint4*)(feat + (size_t)idx[6] * kC + choff);
    uint4 g7 = *(const uint4*)(feat + (size_t)idx[7] * kC + choff);
#define ACC8(g)                                          \
    acc[0] += __uint_as_float((g).x << 16);              \
    acc[1] += __uint_as_float((g).x & 0xffff0000u);      \
    acc[2] += __uint_as_float((g).y << 16);              \
    acc[3] += __uint_as_float((g).y & 0xffff0000u);      \
    acc[4] += __uint_as_float((g).z << 16);              \
    acc[5] += __uint_as_float((g).z & 0xffff0000u);      \
    acc[6] += __uint_as_float((g).w << 16);              \
    acc[7] += __uint_as_float((g).w & 0xffff0000u);
    ACC8(g0)
    ACC8(g1)
    ACC8(g2)
    ACC8(g3)
    ACC8(g4)
    ACC8(g5)
    ACC8(g6)
    ACC8(g7)
#undef ACC8
#pragma unroll
    for (int i = 0; i < 8; ++i) idx[i] = nxt[i];
  }
  if (valid) {
    uint4 o;
    o.x = (unsigned)f2bf(acc[0]) | ((unsigned)f2bf(acc[1]) << 16);
    o.y = (unsigned)f2bf(acc[2]) | ((unsigned)f2bf(acc[3]) << 16);
    o.z = (unsigned)f2bf(acc[4]) | ((unsigned)f2bf(acc[5]) << 16);
    o.w = (unsigned)f2bf(acc[6]) | ((unsigned)f2bf(acc[7]) << 16);
    *(uint4*)(agg + (size_t)slot * kC + choff) = o;
  }
}

// ---- MFMA GEMM v11h: gemm10 + slot-space item tiles + optional fused head.
// agg reads contiguous (slot space); root-feat loads and output stores indirect
// through rlist (sentinel kNI = zero pad row, masked at store). Head: in-register
// dot of the bf16-rounded outputs with lin_w, 16-lane shuffle reduce (validated
// inside fused12, R10 run passed).
__launch_bounds__(256, 4)
__global__ void gemm11h_kernel(int nbi, int do_head,
                               const int* __restrict__ rlist, const int* __restrict__ pcnt,
                               const unsigned short* __restrict__ ag_i, const unsigned short* __restrict__ ft_i,
                               const unsigned short* __restrict__ wc_i, const float* __restrict__ bs_i,
                               const float* __restrict__ gm_i, const float* __restrict__ bt_i,
                               unsigned short* __restrict__ out_i,
                               const unsigned short* __restrict__ ag_u, const unsigned short* __restrict__ ft_u,
                               const unsigned short* __restrict__ wc_u, const float* __restrict__ bs_u,
                               const float* __restrict__ gm_u, const float* __restrict__ bt_u,
                               unsigned short* __restrict__ out_u,
                               const float* __restrict__ lw, const float* __restrict__ lb,
                               float* __restrict__ dout) {
  __shared__ __attribute__((aligned(16))) unsigned short Ws[128 * 128];  // 32 KB
  int b = blockIdx.x;
  bool ind = (b < nbi);
  const unsigned short *agg, *feat, *wcat;
  const float *bias, *gamma, *beta;
  unsigned short* out;
  int N, row0;
  if (ind) {
    agg = ag_i; feat = ft_i; wcat = wc_i; bias = bs_i; gamma = gm_i; beta = bt_i; out = out_i;
    N = kNI; row0 = b * 128;
  } else {
    agg = ag_u; feat = ft_u; wcat = wc_u; bias = bs_u; gamma = gm_u; beta = bt_u; out = out_u;
    N = kNU; row0 = (b - nbi) * 128;
  }
  int cnt = ind ? *pcnt : N;
  if (row0 >= cnt) return;
  int tid = threadIdx.x;
  int lane = tid & 63;
  int wv = tid >> 6;  // 0..3
  int q = lane >> 4;
  int c0 = lane & 15;

  // ---- stage 0: w_rel half (k<128). Each wave stages 8 KB = 8 ops of 1 KB.
  {
    int p0 = lane & 15;
    int rsub = lane >> 4;
#pragma unroll
    for (int o = 0; o < 8; ++o) {
      int n = wv * 32 + o * 4 + rsub;
      int j = p0 ^ (n & 7);
      gload_lds16(wcat + n * 256 + j * 8, &Ws[(wv * 32 + o * 4) * 128]);
    }
  }

  // A preloads (agg half, SLOT space -> contiguous) issued alongside stage0.
  int rs = row0 + wv * 32;  // wave-private 32-slot strip
  int slotA = rs + c0;
  int slotB = rs + 16 + c0;
  int rowAf = ind ? ((slotA < cnt) ? rlist[slotA] : kNI) : slotA;  // feat (root) row
  int rowBf = ind ? ((slotB < cnt) ? rlist[slotB] : kNI) : slotB;
  size_t baseAa = (size_t)slotA * kC;   // agg: slot space
  size_t baseBa = (size_t)slotB * kC;
  size_t baseAf = (size_t)rowAf * kC;   // feat: node space
  size_t baseBf = (size_t)rowBf * kC;
  bf16x8 aA[4], aB[4];
#pragma unroll
  for (int ks = 0; ks < 4; ++ks) {
    aA[ks] = *(const bf16x8*)(agg + baseAa + ks * 32 + q * 8);
    aB[ks] = *(const bf16x8*)(agg + baseBa + ks * 32 + q * 8);
  }
  f32x4 accA[8], accB[8];
#pragma unroll
  for (int nt = 0; nt < 8; ++nt) {
    accA[nt] = (f32x4){0.f, 0.f, 0.f, 0.f};
    accB[nt] = (f32x4){0.f, 0.f, 0.f, 0.f};
  }
  asm volatile("s_waitcnt vmcnt(0)" ::: "memory");
  __syncthreads();

  int rsw = c0 & 7;
  // ---- half 0: B = w_rel, A = agg; prefetch feat A-frags into consumed slots
#pragma unroll
  for (int ks = 0; ks < 4; ++ks) {
    int chp = ((ks * 4 + q) ^ rsw) * 8;
#pragma unroll
    for (int nt = 0; nt < 8; ++nt) {
      bf16x8 bfr = *(const bf16x8*)&Ws[(nt * 16 + c0) * 128 + chp];
      accA[nt] = __builtin_amdgcn_mfma_f32_16x16x32_bf16(aA[ks], bfr, accA[nt], 0, 0, 0);
      accB[nt] = __builtin_amdgcn_mfma_f32_16x16x32_bf16(aB[ks], bfr, accB[nt], 0, 0, 0);
    }
    aA[ks] = *(const bf16x8*)(feat + baseAf + ks * 32 + q * 8);
    aB[ks] = *(const bf16x8*)(feat + baseBf + ks * 32 + q * 8);
  }

  __syncthreads();  // all waves done reading Ws (half 0)
  // ---- stage 1: w_root half (k>=128) into the same buffer
  {
    int p0 = lane & 15;
    int rsub = lane >> 4;
#pragma unroll
    for (int o = 0; o < 8; ++o) {
      int n = wv * 32 + o * 4 + rsub;
      int j = p0 ^ (n & 7);
      gload_lds16(wcat + n * 256 + 128 + j * 8, &Ws[(wv * 32 + o * 4) * 128]);
    }
  }
  asm volatile("s_waitcnt vmcnt(0)" ::: "memory");
  __syncthreads();

  // ---- half 1: B = w_root, A = feat
#pragma unroll
  for (int ks = 0; ks < 4; ++ks) {
    int chp = ((ks * 4 + q) ^ rsw) * 8;
#pragma unroll
    for (int nt = 0; nt < 8; ++nt) {
      bf16x8 bfr = *(const bf16x8*)&Ws[(nt * 16 + c0) * 128 + chp];
      accA[nt] = __builtin_amdgcn_mfma_f32_16x16x32_bf16(aA[ks], bfr, accA[nt], 0, 0, 0);
      accB[nt] = __builtin_amdgcn_mfma_f32_16x16x32_bf16(aB[ks], bfr, accB[nt], 0, 0, 0);
    }
  }

  // LN/head constants loaded AFTER main loop
  float bcol[8], gcol[8], ecol[8], lwc[8];
#pragma unroll
  for (int nt = 0; nt < 8; ++nt) {
    bcol[nt] = bias[nt * 16 + c0];
    gcol[nt] = gamma[nt * 16 + c0];
    ecol[nt] = beta[nt * 16 + c0];
    lwc[nt] = lw[nt * 16 + c0];
  }

  // intra-wave LN epilogue + optional fused head
#pragma unroll
  for (int half = 0; half < 2; ++half) {
    int sbh = rs + half * 16;
#pragma unroll
    for (int reg = 0; reg < 4; ++reg) {
      int slot_r = sbh + q * 4 + reg;
      float v[8];
      float s1 = 0.f, s2 = 0.f;
#pragma unroll
      for (int nt = 0; nt < 8; ++nt) {
        float t = (half ? accB[nt][reg] : accA[nt][reg]) + bcol[nt];
        v[nt] = t;
        s1 += t;
        s2 += t * t;
      }
#pragma unroll
      for (int m = 1; m < 16; m <<= 1) {
        s1 += __shfl_xor(s1, m, 64);
        s2 += __shfl_xor(s2, m, 64);
      }
      float mu = s1 * (1.f / 128.f);
      float var = s2 * (1.f / 128.f) - mu * mu;
      float rsq = rsqrtf(var + 1e-5f);
      int row = ind ? ((slot_r < cnt) ? rlist[slot_r] : N) : slot_r;
      if (row < N) {
        float hs = 0.f;
#pragma unroll
        for (int nt = 0; nt < 8; ++nt) {
          float o = fmaxf((v[nt] - mu) * rsq * gcol[nt] + ecol[nt], 0.f);
          unsigned short h = f2bf(o);
          if (do_head) hs += __uint_as_float((unsigned)h << 16) * lwc[nt];
          unsigned up = __shfl_xor((unsigned)h, 1, 64);
          if ((lane & 1) == 0) {
            *(unsigned*)(out + (size_t)row * kC + nt * 16 + c0) = (unsigned)h | (up << 16);
          }
        }
        if (do_head) {
#pragma unroll
          for (int m = 1; m < 16; m <<= 1) hs += __shfl_xor(hs, m, 64);
          if (c0 == 0) dout[row] = hs + lb[0];
        }
      }
    }
  }
}

extern "C" void kernel_launch(void* const* d_in, const int* in_sizes, int n_in,
                              void* d_out, int out_size, void* d_ws, size_t ws_size,
                              hipStream_t stream) {
  const float* x_user = (const float*)d_in[0];
  const float* x_item = (const float*)d_in[1];
  const int* e_ui_src = (const int*)d_in[2];
  const int* e_ui_dst = (const int*)d_in[3];
  const int* e_iu_src = (const int*)d_in[4];
  const int* e_iu_dst = (const int*)d_in[5];
  const float* w_rel  = (const float*)d_in[6];
  const float* w_root = (const float*)d_in[7];
  const float* bvec   = (const float*)d_in[8];
  const float* ln_g   = (const float*)d_in[9];
  const float* ln_b   = (const float*)d_in[10];
  const float* lin_w  = (const float*)d_in[11];
  const float* lin_b  = (const float*)d_in[12];

  char* p = (char*)d_ws;
  auto carve = [&](size_t bytes) -> char* {
    char* r = p;
    p += (bytes + 255) & ~size_t(255);
    return r;
  };
  // +1 pad row (zeros, written by setup) on each feature table
  unsigned short* fu[2] = {(unsigned short*)carve((size_t)(kNU + 1) * kC * 2),
                           (unsigned short*)carve((size_t)(kNU + 1) * kC * 2)};
  unsigned short* fi[2] = {(unsigned short*)carve((size_t)(kNI + 1) * kC * 2),
                           (unsigned short*)carve((size_t)(kNI + 1) * kC * 2)};
  unsigned short* agg_i = (unsigned short*)carve((size_t)kNI * kC * 2);
  unsigned short* agg_u = (unsigned short*)carve((size_t)kNU * kC * 2);
  unsigned short* wcat  = (unsigned short*)carve((size_t)4 * 128 * 256 * 2);
  int* bh_i   = (int*)carve((size_t)kNBK * 256 * 4);
  int* bo_i   = (int*)carve((size_t)kNBK * 256 * 4);
  int* bh_u   = (int*)carve((size_t)kNBK * 256 * 4);
  int* bo_u   = (int*)carve((size_t)kNBK * 256 * 4);
  int* base_i = (int*)carve(257 * 4);
  int* base_u = (int*)carve(257 * 4);
  unsigned* packed_i = (unsigned*)carve((size_t)kE * 4);
  unsigned* packed_u = (unsigned*)carve((size_t)kE * 4);
  int* col_i    = (int*)carve((size_t)(kE + 4) * 4);
  int* col_u    = (int*)carve((size_t)(kE + 4) * 4);
  int* rowptr_i = (int*)carve((size_t)(kNI + 1) * 4);
  int* rowptr_u = (int*)carve((size_t)(kNU + 1) * 4);
  unsigned* mark = (unsigned*)carve(((kNI + 31) / 32) * 4);
  int* rlist = (int*)carve((size_t)(kMaxNeed + 128) * 4);
  int* cntp  = (int*)carve(4);

  // dispatch 1: cvt + prep_w + needinit
  int cvt4 = (kNU * kC + kNI * kC) / 4 + 128;
  int cvtBlks = (cvt4 + 255) / 256;                       // 18751
  int needBlks = (kMaxNeed + 128 + 255) / 256;            // 21
  setup_kernel<<<cvtBlks + 512 + needBlks, 256, 0, stream>>>(
      x_user, x_item, fu[0], fu[1], fi[0], fi[1], w_rel, w_root, wcat,
      mark, rlist, cntp, cvtBlks);

  // dispatch 2: binA + mark
  int markBlks = (kE + 255) / 256;                        // 1954
  edge_kernel<<<2 * kNBK + markBlks, 256, 0, stream>>>(e_ui_dst, e_iu_dst, bh_i, bh_u,
                                                       e_iu_src, e_iu_dst, mark);
  // dispatch 3: binB + compact
  scan_kernel<<<2 + (kNI + 255) / 256, 256, 0, stream>>>(bh_i, bo_i, base_i,
                                                         bh_u, bo_u, base_u,
                                                         mark, rlist, cntp);
  // dispatch 4-5: CSR scatter + per-bucket sort
  binC_kernel<<<2 * kNBK, 256, 0, stream>>>(e_ui_src, e_ui_dst, bo_i, base_i, packed_i,
                                            e_iu_src, e_iu_dst, bo_u, base_u, packed_u);
  binD_kernel<<<392, 256, 0, stream>>>(packed_i, base_i, col_i, rowptr_i,
                                       packed_u, base_u, col_u, rowptr_u);

  int nbi_p = kMaxNeed / 16;     // 320 item pull blocks (early exit past *cnt)
  int nbi_g = kMaxNeed / 128;    // 40  item gemm blocks (early exit past *cnt)
  int nbu_pB = kB / 16;          // 64  user pull blocks (rows < 1024 only)
  int nbu_gB = kB / 128;         // 8   user gemm blocks (rows < 1024 only)

  // dispatch 6-7: layer 0 (item needed-set in slot space; user rows < kB)
  pull5_kernel<<<nbi_p + nbu_pB, 256, 0, stream>>>(rowptr_i, col_i, fu[0], agg_i,
                                                   rowptr_u, col_u, fi[0], agg_u,
                                                   rlist, cntp, nbi_p);
  gemm11h_kernel<<<nbi_g + nbu_gB, 256, 0, stream>>>(
      nbi_g, 0, rlist, cntp,
      agg_i, fi[0], wcat + (size_t)0 * 128 * 256,
      bvec + (size_t)0 * kC, ln_g + (size_t)1 * kC, ln_b + (size_t)1 * kC, fi[1],
      agg_u, fu[0], wcat + (size_t)1 * 128 * 256,
      bvec + (size_t)1 * kC, ln_g + (size_t)0 * kC, ln_b + (size_t)0 * kC, fu[1],
      lin_w, lin_b, (float*)d_out);

  // dispatch 8-9: layer 1 (user rows < kB only; head fused into gemm)
  pull5_kernel<<<nbu_pB, 256, 0, stream>>>(rowptr_i, col_i, fu[1], agg_i,   // item args unused (nbi=0)
                                           rowptr_u, col_u, fi[1], agg_u,
                                           rlist, cntp, 0);
  gemm11h_kernel<<<nbu_gB, 256, 0, stream>>>(
      0, 1, rlist, cntp,
      agg_i, fi[1], wcat + (size_t)2 * 128 * 256,                            // item args unused (nbi=0)
      bvec + (size_t)2 * kC, ln_g + (size_t)3 * kC, ln_b + (size_t)3 * kC, fi[0],
      agg_u, fu[1], wcat + (size_t)3 * 128 * 256,
      bvec + (size_t)3 * kC, ln_g + (size_t)2 * kC, ln_b + (size_t)2 * kC, fu[0],
      lin_w, lin_b, (float*)d_out);
}